// Round 4
// baseline (806.319 us; speedup 1.0000x reference)
//
#include <hip/hip_runtime.h>

typedef unsigned short u16;
typedef __bf16 bf16x8 __attribute__((ext_vector_type(8)));
typedef unsigned short ushort8 __attribute__((ext_vector_type(8)));
typedef float f32x4 __attribute__((ext_vector_type(4)));

typedef const __attribute__((address_space(1))) void gv_t;  // global
typedef __attribute__((address_space(3))) void lv_t;        // LDS

__device__ __forceinline__ u16 f2bf(float f) {
    union { float f; unsigned u; } x; x.f = f;
    unsigned r = x.u + 0x7fffu + ((x.u >> 16) & 1u);
    return (u16)(r >> 16);
}
__device__ __forceinline__ float bf2f(u16 h) {
    union { unsigned u; float f; } x; x.u = ((unsigned)h) << 16; return x.f;
}
__device__ __forceinline__ bf16x8 as_bf(ushort8 u) {
    union { ushort8 u; bf16x8 b; } x; x.u = u; return x.b;
}

// ---------------- cast f32 -> bf16, both halves in one launch ----------------
__global__ void k_cast2(const float* __restrict__ in0, const float* __restrict__ in1,
                        u16* __restrict__ out0, u16* __restrict__ out1, long nvec) {
    const float* in = blockIdx.y ? in1 : in0;
    u16* out = blockIdx.y ? out1 : out0;
    long i = (long)blockIdx.x * blockDim.x + threadIdx.x;
    long stride = (long)gridDim.x * blockDim.x;
    for (; i < nvec; i += stride) {
        float4 v = ((const float4*)in)[i];
        u16 o[4] = {f2bf(v.x), f2bf(v.y), f2bf(v.z), f2bf(v.w)};
        *(unsigned long long*)(out + i * 4) = *(unsigned long long*)o;
    }
}

// ---------------- transpose+cast: in f32 [R,C] -> out bf16 [C,R] ----------------
__global__ void k_castT(const float* __restrict__ in, u16* __restrict__ out,
                        int R, int C) {
    __shared__ u16 tile[32][33];
    int c0 = blockIdx.x * 32, r0 = blockIdx.y * 32;
    int tx = threadIdx.x, ty = threadIdx.y;
#pragma unroll
    for (int i = 0; i < 4; i++)
        tile[ty + 8 * i][tx] = f2bf(in[(size_t)(r0 + ty + 8 * i) * C + c0 + tx]);
    __syncthreads();
#pragma unroll
    for (int i = 0; i < 4; i++)
        out[(size_t)(c0 + ty + 8 * i) * R + r0 + tx] = tile[tx][ty + 8 * i];
}

// ---------------- GEMM: C[M,N] = A[M,K] @ Bt[N,K]^T (+bias) ----------------
// BK=64 K-step, async global->LDS DMA, LDS [128][64] with XOR chunk swizzle:
// logical 16B chunk c of row r lives at position c^(r&7). Staging keeps the LDS
// dest linear (gload_lds requires base+lane*16) and inverse-swizzles the GLOBAL
// source chunk instead (rule: both-sides-or-neither). Fragment ds_read_b128 is
// then exactly 8 dwords/bank = conflict-free.
// EPI 0: f32 store (+bias). EPI 1: neg-list remap f32. EPI 2: split-K partial
// store to Cs[kc][1024][ldc]. EPI 3: bf16 store (+bias).
template <int EPI>
__global__ __launch_bounds__(256, 2) void gemm_bt(
    const u16* A0, const u16* A1, const u16* __restrict__ Bt,
    const float* __restrict__ bias, u16* H0, u16* H1, float* C0, float* C1,
    int lda, int ldb, long long ldc, int n_tiles, int Kchunk,
    const int* __restrict__ labels) {
    __shared__ u16 Al[128 * 64];
    __shared__ u16 Bl[128 * 64];
    const int bx = blockIdx.x;
    const int by = blockIdx.y % n_tiles;
    const int kc = blockIdx.y / n_tiles;
    const int half = blockIdx.z;
    const u16* A = half ? A1 : A0;
    const int m0 = bx * 128, n0 = by * 128;
    const int t = threadIdx.x;
    const int w = t >> 6, l = t & 63;
    const int wm = (w & 1) * 64, wn = (w >> 1) * 64;
    const int quad = l >> 4, ln = l & 15;
    const int srow = t >> 3;        // 0..31 (row within 32-row staging group)
    const int spos = t & 7;         // LDS 16B-chunk position within row

    f32x4 acc[4][4];
#pragma unroll
    for (int i = 0; i < 4; i++)
#pragma unroll
        for (int j = 0; j < 4; j++) acc[i][j] = f32x4{};

    const int swz = ln & 7;  // row&7 for all fragment rows this lane reads

    const int k_begin = kc * Kchunk;
    for (int k0 = k_begin; k0 < k_begin + Kchunk; k0 += 64) {
        if (k0 != k_begin) __syncthreads();  // readers of previous tile done
#pragma unroll
        for (int i = 0; i < 4; i++) {
            int r = i * 32 + srow;                 // tile row 0..127
            int c = (spos ^ (r & 7)) * 8;          // inverse-swizzled src chunk
            __builtin_amdgcn_global_load_lds(
                (gv_t*)(A + (size_t)(m0 + r) * lda + k0 + c),
                (lv_t*)(Al + i * 2048 + t * 8), 16, 0, 0);
            __builtin_amdgcn_global_load_lds(
                (gv_t*)(Bt + (size_t)(n0 + r) * ldb + k0 + c),
                (lv_t*)(Bl + i * 2048 + t * 8), 16, 0, 0);
        }
        __syncthreads();  // drains vmcnt(0): staged tile visible to all waves
#pragma unroll
        for (int ks = 0; ks < 2; ks++) {
            bf16x8 af[4], bb[4];
#pragma unroll
            for (int i = 0; i < 4; i++) {
                int cc = ((ks * 4 + quad) ^ swz) * 8;  // swizzled read chunk
                af[i] = as_bf(*(const ushort8*)(Al + (wm + i * 16 + ln) * 64 + cc));
                bb[i] = as_bf(*(const ushort8*)(Bl + (wn + i * 16 + ln) * 64 + cc));
            }
#pragma unroll
            for (int i = 0; i < 4; i++)
#pragma unroll
                for (int j = 0; j < 4; j++)
                    acc[i][j] = __builtin_amdgcn_mfma_f32_16x16x32_bf16(af[i], bb[j], acc[i][j], 0, 0, 0);
        }
    }

    u16* Hs = half ? H1 : H0;
    float* Cs = half ? C1 : C0;
#pragma unroll
    for (int i = 0; i < 4; i++) {
        int row = m0 + wm + i * 16 + quad * 4;
#pragma unroll
        for (int j = 0; j < 4; j++) {
            int col = n0 + wn + j * 16 + ln;
            float bv = 0.f;
            if (EPI == 0 || EPI == 3) { if (bias) bv = bias[col]; }
#pragma unroll
            for (int r = 0; r < 4; r++) {
                int rr = row + r;
                float v = acc[i][j][r] + bv;
                if (EPI == 0) {
                    Cs[(size_t)rr * ldc + col] = v;
                } else if (EPI == 3) {
                    Hs[(size_t)rr * ldc + col] = f2bf(v);
                } else if (EPI == 2) {
                    // split-K partial: Cs[kc][rr][col], M=1024 rows
                    Cs[(size_t)kc * (1024 * (size_t)ldc) + (size_t)rr * ldc + col] = v;
                } else {  // EPI 1: neg-list remap: skip own-class cols, shift by 4
                    int L4 = labels[rr] * 4;
                    if (col < L4)
                        Cs[(size_t)rr * ldc + 1032 + col] = v;
                    else if (col >= L4 + 4)
                        Cs[(size_t)rr * ldc + 1032 + col - 4] = v;
                }
            }
        }
    }
}

// ---------------- BatchNorm stats+final fused (H is bf16 in ws) ----------------
__global__ void k_bn(const u16* __restrict__ Hq, const u16* __restrict__ Hk,
                     const float* __restrict__ gamma, const float* __restrict__ beta,
                     float* __restrict__ scale, float* __restrict__ shift) {
    int half = blockIdx.y;
    const u16* H = half ? Hk : Hq;
    int col = blockIdx.x * 256 + threadIdx.x;
    float s = 0.f, s2 = 0.f;
#pragma unroll 8
    for (int r = 0; r < 1024; r++) {
        float v = bf2f(H[(size_t)r * 2048 + col]);
        s += v; s2 += v * v;
    }
    float mu = s * (1.f / 1024.f);
    float var = s2 * (1.f / 1024.f) - mu * mu;
    float sc = gamma[col] * rsqrtf(var + 1e-5f);
    shift[half * 2048 + col] = beta[col] - mu * sc;
    scale[half * 2048 + col] = sc;
}

__global__ void k_bn_apply(u16* Hq, u16* Hk, const float* __restrict__ scale,
                           const float* __restrict__ shift) {
    int row = blockIdx.x, half = blockIdx.y;
    u16* H = half ? Hk : Hq;
    int col = threadIdx.x * 8;
    ushort8 h = *(ushort8*)(H + (size_t)row * 2048 + col);
    ushort8 o;
#pragma unroll
    for (int k = 0; k < 8; k++) {
        float v = bf2f(h[k]) * scale[half * 2048 + col + k] + shift[half * 2048 + col + k];
        o[k] = f2bf(fmaxf(v, 0.f));
    }
    *(ushort8*)(H + (size_t)row * 2048 + col) = o;
}

// ---------------- L2 norm rows (+b2) over split-K partials; fused pos_list ----
__global__ void k_l2norm(const float* __restrict__ Fqp, const float* __restrict__ Fkp,
                         const float* __restrict__ b2, float* fqf, float* fkf,
                         u16* fqh, u16* fkh, const float* __restrict__ pq,
                         const int* __restrict__ lq, float* __restrict__ out0) {
    int row = blockIdx.x, half = blockIdx.y, d = threadIdx.x;
    const float* Fp = half ? Fkp : Fqp;
    float x = b2[d];
#pragma unroll
    for (int kc = 0; kc < 8; kc++)
        x += Fp[(size_t)kc * 131072 + (size_t)row * 128 + d];
    float ss = x * x;
#pragma unroll
    for (int off = 32; off >= 1; off >>= 1) ss += __shfl_down(ss, off);
    __shared__ float p[2];
    if ((threadIdx.x & 63) == 0) p[threadIdx.x >> 6] = ss;
    __syncthreads();
    float n = sqrtf(p[0] + p[1]);
    float v = x / fmaxf(n, 1e-12f);
    (half ? fkf : fqf)[(size_t)row * 128 + d] = v;
    (half ? fkh : fqh)[(size_t)row * 128 + d] = f2bf(v);

    if (half == 0) {  // block-uniform branch: fused pos_list
        int base = lq[row] * 8;
        const float* pp = pq + (size_t)d * 65536 + base;
        float4 v0 = *(const float4*)pp;
        float4 v1 = *(const float4*)(pp + 4);
        float a[8] = {v * v0.x, v * v0.y, v * v0.z, v * v0.w,
                      v * v1.x, v * v1.y, v * v1.z, v * v1.w};
#pragma unroll
        for (int off = 32; off >= 1; off >>= 1)
#pragma unroll
            for (int q = 0; q < 8; q++) a[q] += __shfl_down(a[q], off);
        __shared__ float pr[2][8];
        if ((threadIdx.x & 63) == 0) {
#pragma unroll
            for (int q = 0; q < 8; q++) pr[threadIdx.x >> 6][q] = a[q];
        }
        __syncthreads();
        if (threadIdx.x < 8)
            out0[(size_t)row * 33796 + 1024 + threadIdx.x] =
                pr[0][threadIdx.x] + pr[1][threadIdx.x];
    }
}

// ---------------- labels_con fill (f32) ----------------
__global__ void k_labels(const int* __restrict__ lq, const int* __restrict__ lk,
                         float* __restrict__ out1) {
    int b = blockIdx.y;
    int j0 = (blockIdx.x * 256 + threadIdx.x) * 8;
    if (j0 >= 33796) return;
    float* o = out1 + (size_t)b * 33796;
    if (j0 >= 1032 && j0 + 8 <= 33796) {
        float4 z = {0.f, 0.f, 0.f, 0.f};
        *(float4*)(o + j0) = z;
        *(float4*)(o + j0 + 4) = z;
    } else {
        int Lq = lq[b];
        for (int k = 0; k < 8 && j0 + k < 33796; k++) {
            int j = j0 + k;
            o[j] = (j < 1024) ? ((Lq == lk[j]) ? 1.f : 0.f) : (j < 1032 ? 1.f : 0.f);
        }
    }
}

// ---------------- two f32 vector copies in one launch ----------------
__global__ void k_copy2(const float* __restrict__ s1, float* __restrict__ d1, long n1,
                        const float* __restrict__ s2, float* __restrict__ d2, long n2) {
    long i = (long)blockIdx.x * blockDim.x + threadIdx.x;
    long stride = (long)gridDim.x * blockDim.x;
    long tot = n1 + n2;
    for (; i < tot; i += stride) {
        if (i < n1) ((float4*)d1)[i] = ((const float4*)s1)[i];
        else ((float4*)d2)[i - n1] = ((const float4*)s2)[i - n1];
    }
}

// ---------------- queue bookkeeping (8-way parallel rank) ----------------
__global__ void k_rank(const int* __restrict__ lk, const int* __restrict__ nptr,
                       const int* __restrict__ pptr, int* __restrict__ counts,
                       int* __restrict__ colN, int* __restrict__ colP) {
    __shared__ int lab[1024];
    int tid = threadIdx.x;  // 128 threads
    for (int i = tid; i < 1024; i += 128) lab[i] = lk[i];
    __syncthreads();
    int b = blockIdx.x * 128 + tid;
    int c = lab[b];
    int rank = 0, count = 0;
    for (int i = 0; i < 1024; i++) {
        int m = (lab[i] == c);
        count += m;
        rank += (i < b) ? m : 0;
    }
    if (rank == count - 1) counts[c] = count;
    colN[b] = (rank >= count - 4) ? c * 4 + (nptr[c] + rank) % 4 : -1;
    colP[b] = (rank >= count - 8) ? c * 8 + (pptr[c] + rank) % 8 : -1;
}

// scatter (blocks 0..511, 2 rows each) + ptr outputs (blocks 512..543)
__global__ void k_scatter_ptrs(const float* __restrict__ fkf,
                               const int* __restrict__ colN, const int* __restrict__ colP,
                               const int* __restrict__ nptr, const int* __restrict__ pptr,
                               const int* __restrict__ counts,
                               float* outN, float* outP, float* outNp, float* outPp) {
    int bid = blockIdx.x;
    if (bid < 512) {
        int b = bid * 2 + (threadIdx.x >> 7);
        int d = threadIdx.x & 127;
        float v = fkf[(size_t)b * 128 + d];
        int cn = colN[b];
        if (cn >= 0) outN[(size_t)d * 32768 + cn] = v;
        int cp = colP[b];
        if (cp >= 0) outP[(size_t)d * 65536 + cp] = v;
    } else {
        int c = (bid - 512) * 256 + threadIdx.x;
        int cnt = counts[c];
        outNp[c] = (float)((nptr[c] + cnt) & 3);
        outPp[c] = (float)((pptr[c] + cnt) & 7);
    }
}

// ---------------- host ----------------
extern "C" void kernel_launch(void* const* d_in, const int* in_sizes, int n_in,
                              void* d_out, int out_size, void* d_ws, size_t ws_size,
                              hipStream_t stream) {
    const float* midq = (const float*)d_in[0];
    const float* midk = (const float*)d_in[1];
    const int* lq     = (const int*)d_in[2];
    const int* lk     = (const int*)d_in[3];
    const float* W1   = (const float*)d_in[4];
    const float* b1   = (const float*)d_in[5];
    const float* gamma= (const float*)d_in[6];
    const float* beta = (const float*)d_in[7];
    const float* W2   = (const float*)d_in[8];
    const float* b2   = (const float*)d_in[9];
    const float* Wlin = (const float*)d_in[10];
    const float* blin = (const float*)d_in[11];
    const float* nq   = (const float*)d_in[12];
    const float* pq   = (const float*)d_in[13];
    const int* nptr   = (const int*)d_in[14];
    const int* pptr   = (const int*)d_in[15];
    (void)in_sizes; (void)n_in; (void)out_size; (void)ws_size;

    float* out = (float*)d_out;
    const size_t O0 = 0;
    const size_t O1 = 34607104;   // labels_con
    const size_t O2 = 69214208;   // logit_q
    const size_t O3 = 77602816;   // logit_k
    const size_t O4 = 85991424;   // neg_queue2
    const size_t O5 = 90185728;   // pos_queue2
    const size_t O6 = 98574336;   // neg_ptr2
    const size_t O7 = 98582528;   // pos_ptr2

    char* ws = (char*)d_ws;
    size_t off = 0;
    auto alloc = [&](size_t bytes) -> char* {
        char* p = ws + off;
        off = (off + bytes + 255) & ~(size_t)255;
        return p;
    };
    u16* W1t   = (u16*)alloc((size_t)2048 * 2048 * 2);
    u16* WlinT = (u16*)alloc((size_t)8192 * 2048 * 2);
    u16* W2t   = (u16*)alloc((size_t)128 * 2048 * 2);
    u16* nqT   = (u16*)alloc((size_t)32768 * 128 * 2);
    u16* midqh = (u16*)alloc((size_t)1024 * 2048 * 2);
    u16* midkh = (u16*)alloc((size_t)1024 * 2048 * 2);
    u16* Hq    = (u16*)alloc((size_t)1024 * 2048 * 2);
    u16* Hk    = (u16*)alloc((size_t)1024 * 2048 * 2);
    float* Fq  = (float*)alloc((size_t)8 * 1024 * 128 * 4);  // split-K partials
    float* Fk  = (float*)alloc((size_t)8 * 1024 * 128 * 4);
    float* fqf = (float*)alloc((size_t)1024 * 128 * 4);
    float* fkf = (float*)alloc((size_t)1024 * 128 * 4);
    u16* fqh   = (u16*)alloc((size_t)1024 * 128 * 2);
    u16* fkh   = (u16*)alloc((size_t)1024 * 128 * 2);
    float* scaleA = (float*)alloc((size_t)2 * 2048 * 4);
    float* shiftA = (float*)alloc((size_t)2 * 2048 * 4);
    int* counts = (int*)alloc(8192 * 4);
    int* colN   = (int*)alloc(1024 * 4);
    int* colP   = (int*)alloc(1024 * 4);

    // casts / transposes to bf16
    k_cast2<<<dim3(1024, 2), 256, 0, stream>>>(midq, midk, midqh, midkh,
                                               (long)1024 * 2048 / 4);
    dim3 tb(32, 8);
    k_castT<<<dim3(64, 64), tb, 0, stream>>>(W1, W1t, 2048, 2048);
    k_castT<<<dim3(256, 64), tb, 0, stream>>>(Wlin, WlinT, 2048, 8192);
    k_castT<<<dim3(4, 64), tb, 0, stream>>>(W2, W2t, 2048, 128);
    k_castT<<<dim3(1024, 4), tb, 0, stream>>>(nq, nqT, 128, 32768);

    // H = X @ W1 + b1 (bf16 out, both halves)
    gemm_bt<3><<<dim3(8, 16, 2), 256, 0, stream>>>(midqh, midkh, W1t, b1, Hq, Hk,
        nullptr, nullptr, 2048, 2048, 2048, 16, 2048, nullptr);

    k_bn<<<dim3(8, 2), 256, 0, stream>>>(Hq, Hk, gamma, beta, scaleA, shiftA);
    k_bn_apply<<<dim3(1024, 2), 256, 0, stream>>>(Hq, Hk, scaleA, shiftA);

    hipMemsetAsync(counts, 0, 8192 * 4, stream);

    // F = G @ W2 (split-K=8, partial stores; reduced in k_l2norm)
    gemm_bt<2><<<dim3(8, 8, 2), 256, 0, stream>>>(Hq, Hk, W2t, nullptr, nullptr,
        nullptr, Fq, Fk, 2048, 2048, 128, 1, 256, nullptr);

    k_l2norm<<<dim3(1024, 2), 128, 0, stream>>>(Fq, Fk, b2, fqf, fkf, fqh, fkh,
                                                pq, lq, out + O0);

    // sim_batch = feat_q @ feat_k^T  -> out cols [0,1024)
    gemm_bt<0><<<dim3(8, 8, 1), 256, 0, stream>>>(fqh, fqh, fkh, nullptr,
        nullptr, nullptr, out + O0, out + O0, 128, 128, 33796, 8, 128, nullptr);

    // neg_list -> out cols [1032,33796) with per-row column remap
    gemm_bt<1><<<dim3(8, 256, 1), 256, 0, stream>>>(fqh, fqh, nqT, nullptr,
        nullptr, nullptr, out + O0, out + O0, 128, 128, 33796, 256, 128, lq);

    k_labels<<<dim3(17, 1024), 256, 0, stream>>>(lq, lk, out + O1);

    // logits = X @ Wlin + blin (both halves)
    gemm_bt<0><<<dim3(8, 64, 2), 256, 0, stream>>>(midqh, midkh, WlinT, blin,
        nullptr, nullptr, out + O2, out + O3, 2048, 2048, 8192, 64, 2048, nullptr);

    k_copy2<<<2048, 256, 0, stream>>>(nq, out + O4, 4194304 / 4,
                                      pq, out + O5, 8388608 / 4);

    k_rank<<<8, 128, 0, stream>>>(lk, nptr, pptr, counts, colN, colP);
    k_scatter_ptrs<<<544, 256, 0, stream>>>(fkf, colN, colP, nptr, pptr, counts,
                                            out + O4, out + O5, out + O6, out + O7);
}

// Round 5
// 766.118 us; speedup vs baseline: 1.0525x; 1.0525x over previous
//
#include <hip/hip_runtime.h>

typedef unsigned short u16;
typedef __bf16 bf16x8 __attribute__((ext_vector_type(8)));
typedef unsigned short ushort8 __attribute__((ext_vector_type(8)));
typedef float f32x4 __attribute__((ext_vector_type(4)));

typedef const __attribute__((address_space(1))) void gv_t;  // global
typedef __attribute__((address_space(3))) void lv_t;        // LDS

__device__ __forceinline__ u16 f2bf(float f) {
    union { float f; unsigned u; } x; x.f = f;
    unsigned r = x.u + 0x7fffu + ((x.u >> 16) & 1u);
    return (u16)(r >> 16);
}
__device__ __forceinline__ float bf2f(u16 h) {
    union { unsigned u; float f; } x; x.u = ((unsigned)h) << 16; return x.f;
}
__device__ __forceinline__ bf16x8 as_bf(ushort8 u) {
    union { ushort8 u; bf16x8 b; } x; x.u = u; return x.b;
}

// ---------------- cast f32 -> bf16, both halves in one launch ----------------
__global__ void k_cast2(const float* __restrict__ in0, const float* __restrict__ in1,
                        u16* __restrict__ out0, u16* __restrict__ out1, long nvec) {
    const float* in = blockIdx.y ? in1 : in0;
    u16* out = blockIdx.y ? out1 : out0;
    long i = (long)blockIdx.x * blockDim.x + threadIdx.x;
    long stride = (long)gridDim.x * blockDim.x;
    for (; i < nvec; i += stride) {
        float4 v = ((const float4*)in)[i];
        u16 o[4] = {f2bf(v.x), f2bf(v.y), f2bf(v.z), f2bf(v.w)};
        *(unsigned long long*)(out + i * 4) = *(unsigned long long*)o;
    }
}

// ---------------- transpose+cast: in f32 [R,C] -> out bf16 [C,R] ----------------
__global__ void k_castT(const float* __restrict__ in, u16* __restrict__ out,
                        int R, int C) {
    __shared__ u16 tile[32][33];
    int c0 = blockIdx.x * 32, r0 = blockIdx.y * 32;
    int tx = threadIdx.x, ty = threadIdx.y;
#pragma unroll
    for (int i = 0; i < 4; i++)
        tile[ty + 8 * i][tx] = f2bf(in[(size_t)(r0 + ty + 8 * i) * C + c0 + tx]);
    __syncthreads();
#pragma unroll
    for (int i = 0; i < 4; i++)
        out[(size_t)(c0 + ty + 8 * i) * R + r0 + tx] = tile[tx][ty + 8 * i];
}

// ---------------- GEMM: C[M,N] = A[M,K] @ Bt[N,K]^T (+bias) ----------------
// m97 structure: BK=32, linear LDS [128][32], async global->LDS DMA (16B/lane).
// EPI 2: split-K partial store to Cs[kc][1024][ldc] (F = G @ W2).
// EPI 4: merged H+logits. B is the CONTIGUOUS concat [W1t|WlinT] (10240 rows,
//        ldb=2048). by<16 -> H bf16 store (+bias=b1, ld 2048); by>=16 ->
//        logits f32 store (+bias2=blin, ld 8192). XCD-bijective block swizzle:
//        each XCD owns a 10-tile B-band (~5MB) for L2 residency of WlinT.
// EPI 5: merged sim_batch+neg_list (K=128). by<8 -> sim f32 store to
//        out[rr*33796 + by*128+cl]; by>=8 -> B=Bt2 (nqT), neg-list remap.
template <int EPI>
__global__ __launch_bounds__(256, 2) void gemm_bt(
    const u16* A0, const u16* A1, const u16* __restrict__ Bt,
    const u16* __restrict__ Bt2, const float* __restrict__ bias,
    const float* __restrict__ bias2, u16* H0, u16* H1, float* C0, float* C1,
    int lda, int ldb, long long ldc, int n_tiles, int Kchunk,
    const int* __restrict__ labels) {
    __shared__ u16 Al[128 * 32];
    __shared__ u16 Bl[128 * 32];

    int bx, by, kc, half;
    if (EPI == 4) {
        // grid (8,80,2) -> 1280 blocks. XCD x gets by-band [x*10, x*10+10).
        int pid = blockIdx.x + blockIdx.y * 8 + blockIdx.z * 640;
        int xcd = pid & 7, idx = pid >> 3;   // idx 0..159
        by = xcd * 10 + idx % 10;
        int rem = idx / 10;                  // 0..15
        bx = rem & 7; half = rem >> 3; kc = 0;
    } else if (EPI == 5) {
        bx = blockIdx.x; by = blockIdx.y; kc = 0; half = 0;
    } else {
        bx = blockIdx.x; by = blockIdx.y % n_tiles; kc = blockIdx.y / n_tiles;
        half = blockIdx.z;
    }
    const u16* A = half ? A1 : A0;

    // B select + B row base
    const u16* B = Bt;
    int bn0 = by * 128;
    if (EPI == 5 && by >= 8) { B = Bt2; bn0 = (by - 8) * 128; }

    const int m0 = bx * 128;
    const int t = threadIdx.x;
    const int w = t >> 6, l = t & 63;
    const int wm = (w & 1) * 64, wn = (w >> 1) * 64;
    const int quad = l >> 4, ln = l & 15;
    const int srow = t >> 2;        // 0..63 (row within 64-row half-panel)
    const int sk = (t & 3) * 8;     // k-chunk within 32

    f32x4 acc[4][4];
#pragma unroll
    for (int i = 0; i < 4; i++)
#pragma unroll
        for (int j = 0; j < 4; j++) acc[i][j] = f32x4{};

    // wave-uniform LDS bases for staging (16 rows x 32 u16 = 1024 B per wave)
    u16* lAw = Al + (w << 4) * 32;
    u16* lBw = Bl + (w << 4) * 32;

    const int k_begin = kc * Kchunk;
    for (int k0 = k_begin; k0 < k_begin + Kchunk; k0 += 32) {
        if (k0 != k_begin) __syncthreads();  // readers of previous tile done
#pragma unroll
        for (int i = 0; i < 2; i++) {
            __builtin_amdgcn_global_load_lds(
                (gv_t*)(A + (size_t)(m0 + srow + i * 64) * lda + k0 + sk),
                (lv_t*)(lAw + i * 64 * 32), 16, 0, 0);
            __builtin_amdgcn_global_load_lds(
                (gv_t*)(B + (size_t)(bn0 + srow + i * 64) * ldb + k0 + sk),
                (lv_t*)(lBw + i * 64 * 32), 16, 0, 0);
        }
        __syncthreads();  // drains vmcnt(0): staged tile visible to all waves
        bf16x8 af[4], bb[4];
#pragma unroll
        for (int i = 0; i < 4; i++) {
            af[i] = as_bf(*(const ushort8*)(Al + (wm + i * 16 + ln) * 32 + quad * 8));
            bb[i] = as_bf(*(const ushort8*)(Bl + (wn + i * 16 + ln) * 32 + quad * 8));
        }
#pragma unroll
        for (int i = 0; i < 4; i++)
#pragma unroll
            for (int j = 0; j < 4; j++)
                acc[i][j] = __builtin_amdgcn_mfma_f32_16x16x32_bf16(af[i], bb[j], acc[i][j], 0, 0, 0);
    }

#pragma unroll
    for (int i = 0; i < 4; i++) {
        int row = m0 + wm + i * 16 + quad * 4;
#pragma unroll
        for (int j = 0; j < 4; j++) {
            int cl = wn + j * 16 + ln;   // 0..127 within tile
#pragma unroll
            for (int r = 0; r < 4; r++) {
                int rr = row + r;
                float v = acc[i][j][r];
                if (EPI == 2) {
                    int col = by * 128 + cl;
                    float* Cs = half ? C1 : C0;
                    Cs[(size_t)kc * (1024 * (size_t)ldc) + (size_t)rr * ldc + col] = v;
                } else if (EPI == 4) {
                    if (by < 16) {       // H half: bf16 + b1
                        int col = by * 128 + cl;
                        u16* Hs = half ? H1 : H0;
                        Hs[(size_t)rr * 2048 + col] = f2bf(v + bias[col]);
                    } else {             // logits: f32 + blin
                        int col = (by - 16) * 128 + cl;
                        float* Cs = half ? C1 : C0;
                        Cs[(size_t)rr * 8192 + col] = v + bias2[col];
                    }
                } else if (EPI == 5) {
                    if (by < 8) {        // sim_batch -> cols [0,1024)
                        int col = by * 128 + cl;
                        C0[(size_t)rr * 33796 + col] = v;
                    } else {             // neg-list remap, skip own-class cols
                        int col = (by - 8) * 128 + cl;
                        int L4 = labels[rr] * 4;
                        if (col < L4)
                            C0[(size_t)rr * 33796 + 1032 + col] = v;
                        else if (col >= L4 + 4)
                            C0[(size_t)rr * 33796 + 1032 + col - 4] = v;
                    }
                }
            }
        }
    }
}

// ---------------- BatchNorm (H is bf16 in ws) ----------------
__global__ void k_bn_stats(const u16* __restrict__ Hq, const u16* __restrict__ Hk,
                           float* __restrict__ ps, float* __restrict__ ps2) {
    int half = blockIdx.z;
    const u16* H = half ? Hk : Hq;
    int col = blockIdx.x * 256 + threadIdx.x;
    int r0 = blockIdx.y * 64;
    float s = 0.f, s2 = 0.f;
    for (int r = 0; r < 64; r++) {
        float v = bf2f(H[(size_t)(r0 + r) * 2048 + col]);
        s += v; s2 += v * v;
    }
    size_t o = ((size_t)half * 16 + blockIdx.y) * 2048 + col;
    ps[o] = s; ps2[o] = s2;
}

__global__ void k_bn_final(const float* __restrict__ ps, const float* __restrict__ ps2,
                           const float* __restrict__ gamma, const float* __restrict__ beta,
                           float* __restrict__ scale, float* __restrict__ shift) {
    int idx = blockIdx.x * 256 + threadIdx.x;  // 0..4095
    int half = idx >> 11, col = idx & 2047;
    float s = 0.f, s2 = 0.f;
    for (int rb = 0; rb < 16; rb++) {
        size_t o = ((size_t)half * 16 + rb) * 2048 + col;
        s += ps[o]; s2 += ps2[o];
    }
    float mu = s * (1.f / 1024.f);
    float var = s2 * (1.f / 1024.f) - mu * mu;
    float sc = gamma[col] * rsqrtf(var + 1e-5f);
    shift[half * 2048 + col] = beta[col] - mu * sc;
    scale[half * 2048 + col] = sc;
}

__global__ void k_bn_apply(u16* Hq, u16* Hk, const float* __restrict__ scale,
                           const float* __restrict__ shift) {
    int row = blockIdx.x, half = blockIdx.y;
    u16* H = half ? Hk : Hq;
    int col = threadIdx.x * 8;
    ushort8 h = *(ushort8*)(H + (size_t)row * 2048 + col);
    ushort8 o;
#pragma unroll
    for (int k = 0; k < 8; k++) {
        float v = bf2f(h[k]) * scale[half * 2048 + col + k] + shift[half * 2048 + col + k];
        o[k] = f2bf(fmaxf(v, 0.f));
    }
    *(ushort8*)(H + (size_t)row * 2048 + col) = o;
}

// ---------------- L2 norm rows (+b2) over split-K partials; fused pos_list ----
__global__ void k_l2norm(const float* __restrict__ Fqp, const float* __restrict__ Fkp,
                         const float* __restrict__ b2, float* fqf, float* fkf,
                         u16* fqh, u16* fkh, const float* __restrict__ pq,
                         const int* __restrict__ lq, float* __restrict__ out0) {
    int row = blockIdx.x, half = blockIdx.y, d = threadIdx.x;
    const float* Fp = half ? Fkp : Fqp;
    float x = b2[d];
#pragma unroll
    for (int kc = 0; kc < 8; kc++)
        x += Fp[(size_t)kc * 131072 + (size_t)row * 128 + d];
    float ss = x * x;
#pragma unroll
    for (int off = 32; off >= 1; off >>= 1) ss += __shfl_down(ss, off);
    __shared__ float p[2];
    if ((threadIdx.x & 63) == 0) p[threadIdx.x >> 6] = ss;
    __syncthreads();
    float n = sqrtf(p[0] + p[1]);
    float v = x / fmaxf(n, 1e-12f);
    (half ? fkf : fqf)[(size_t)row * 128 + d] = v;
    (half ? fkh : fqh)[(size_t)row * 128 + d] = f2bf(v);

    if (half == 0) {  // block-uniform branch: fused pos_list
        int base = lq[row] * 8;
        const float* pp = pq + (size_t)d * 65536 + base;
        float4 v0 = *(const float4*)pp;
        float4 v1 = *(const float4*)(pp + 4);
        float a[8] = {v * v0.x, v * v0.y, v * v0.z, v * v0.w,
                      v * v1.x, v * v1.y, v * v1.z, v * v1.w};
#pragma unroll
        for (int off = 32; off >= 1; off >>= 1)
#pragma unroll
            for (int q = 0; q < 8; q++) a[q] += __shfl_down(a[q], off);
        __shared__ float pr[2][8];
        if ((threadIdx.x & 63) == 0) {
#pragma unroll
            for (int q = 0; q < 8; q++) pr[threadIdx.x >> 6][q] = a[q];
        }
        __syncthreads();
        if (threadIdx.x < 8)
            out0[(size_t)row * 33796 + 1024 + threadIdx.x] =
                pr[0][threadIdx.x] + pr[1][threadIdx.x];
    }
}

// ---------------- labels_con fill (f32) ----------------
__global__ void k_labels(const int* __restrict__ lq, const int* __restrict__ lk,
                         float* __restrict__ out1) {
    int b = blockIdx.y;
    int j0 = (blockIdx.x * 256 + threadIdx.x) * 8;
    if (j0 >= 33796) return;
    float* o = out1 + (size_t)b * 33796;
    if (j0 >= 1032 && j0 + 8 <= 33796) {
        float4 z = {0.f, 0.f, 0.f, 0.f};
        *(float4*)(o + j0) = z;
        *(float4*)(o + j0 + 4) = z;
    } else {
        int Lq = lq[b];
        for (int k = 0; k < 8 && j0 + k < 33796; k++) {
            int j = j0 + k;
            o[j] = (j < 1024) ? ((Lq == lk[j]) ? 1.f : 0.f) : (j < 1032 ? 1.f : 0.f);
        }
    }
}

// ---------------- two f32 vector copies in one launch ----------------
__global__ void k_copy2(const float* __restrict__ s1, float* __restrict__ d1, long n1,
                        const float* __restrict__ s2, float* __restrict__ d2, long n2) {
    long i = (long)blockIdx.x * blockDim.x + threadIdx.x;
    long stride = (long)gridDim.x * blockDim.x;
    long tot = n1 + n2;
    for (; i < tot; i += stride) {
        if (i < n1) ((float4*)d1)[i] = ((const float4*)s1)[i];
        else ((float4*)d2)[i - n1] = ((const float4*)s2)[i - n1];
    }
}

// ---------------- queue bookkeeping (8-way parallel rank) ----------------
__global__ void k_rank(const int* __restrict__ lk, const int* __restrict__ nptr,
                       const int* __restrict__ pptr, int* __restrict__ counts,
                       int* __restrict__ colN, int* __restrict__ colP) {
    __shared__ int lab[1024];
    int tid = threadIdx.x;  // 128 threads
    for (int i = tid; i < 1024; i += 128) lab[i] = lk[i];
    __syncthreads();
    int b = blockIdx.x * 128 + tid;
    int c = lab[b];
    int rank = 0, count = 0;
    for (int i = 0; i < 1024; i++) {
        int m = (lab[i] == c);
        count += m;
        rank += (i < b) ? m : 0;
    }
    if (rank == count - 1) counts[c] = count;
    colN[b] = (rank >= count - 4) ? c * 4 + (nptr[c] + rank) % 4 : -1;
    colP[b] = (rank >= count - 8) ? c * 8 + (pptr[c] + rank) % 8 : -1;
}

// scatter (blocks 0..511, 2 rows each) + ptr outputs (blocks 512..543)
__global__ void k_scatter_ptrs(const float* __restrict__ fkf,
                               const int* __restrict__ colN, const int* __restrict__ colP,
                               const int* __restrict__ nptr, const int* __restrict__ pptr,
                               const int* __restrict__ counts,
                               float* outN, float* outP, float* outNp, float* outPp) {
    int bid = blockIdx.x;
    if (bid < 512) {
        int b = bid * 2 + (threadIdx.x >> 7);
        int d = threadIdx.x & 127;
        float v = fkf[(size_t)b * 128 + d];
        int cn = colN[b];
        if (cn >= 0) outN[(size_t)d * 32768 + cn] = v;
        int cp = colP[b];
        if (cp >= 0) outP[(size_t)d * 65536 + cp] = v;
    } else {
        int c = (bid - 512) * 256 + threadIdx.x;
        int cnt = counts[c];
        outNp[c] = (float)((nptr[c] + cnt) & 3);
        outPp[c] = (float)((pptr[c] + cnt) & 7);
    }
}

// ---------------- host ----------------
extern "C" void kernel_launch(void* const* d_in, const int* in_sizes, int n_in,
                              void* d_out, int out_size, void* d_ws, size_t ws_size,
                              hipStream_t stream) {
    const float* midq = (const float*)d_in[0];
    const float* midk = (const float*)d_in[1];
    const int* lq     = (const int*)d_in[2];
    const int* lk     = (const int*)d_in[3];
    const float* W1   = (const float*)d_in[4];
    const float* b1   = (const float*)d_in[5];
    const float* gamma= (const float*)d_in[6];
    const float* beta = (const float*)d_in[7];
    const float* W2   = (const float*)d_in[8];
    const float* b2   = (const float*)d_in[9];
    const float* Wlin = (const float*)d_in[10];
    const float* blin = (const float*)d_in[11];
    const float* nq   = (const float*)d_in[12];
    const float* pq   = (const float*)d_in[13];
    const int* nptr   = (const int*)d_in[14];
    const int* pptr   = (const int*)d_in[15];
    (void)in_sizes; (void)n_in; (void)out_size; (void)ws_size;

    float* out = (float*)d_out;
    const size_t O0 = 0;
    const size_t O1 = 34607104;   // labels_con
    const size_t O2 = 69214208;   // logit_q
    const size_t O3 = 77602816;   // logit_k
    const size_t O4 = 85991424;   // neg_queue2
    const size_t O5 = 90185728;   // pos_queue2
    const size_t O6 = 98574336;   // neg_ptr2
    const size_t O7 = 98582528;   // pos_ptr2

    char* ws = (char*)d_ws;
    size_t off = 0;
    auto alloc = [&](size_t bytes) -> char* {
        char* p = ws + off;
        off = (off + bytes + 255) & ~(size_t)255;
        return p;
    };
    // NOTE: W1t and WlinT MUST stay adjacent (contiguous [10240][2048] concat
    // for the merged H+logits GEMM). 2048*2048*2 = 8388608 is 256-aligned.
    u16* W1t   = (u16*)alloc((size_t)2048 * 2048 * 2);
    u16* WlinT = (u16*)alloc((size_t)8192 * 2048 * 2);
    u16* W2t   = (u16*)alloc((size_t)128 * 2048 * 2);
    u16* nqT   = (u16*)alloc((size_t)32768 * 128 * 2);
    u16* midqh = (u16*)alloc((size_t)1024 * 2048 * 2);
    u16* midkh = (u16*)alloc((size_t)1024 * 2048 * 2);
    u16* Hq    = (u16*)alloc((size_t)1024 * 2048 * 2);
    u16* Hk    = (u16*)alloc((size_t)1024 * 2048 * 2);
    float* Fq  = (float*)alloc((size_t)8 * 1024 * 128 * 4);  // split-K partials
    float* Fk  = (float*)alloc((size_t)8 * 1024 * 128 * 4);
    float* fqf = (float*)alloc((size_t)1024 * 128 * 4);
    float* fkf = (float*)alloc((size_t)1024 * 128 * 4);
    u16* fqh   = (u16*)alloc((size_t)1024 * 128 * 2);
    u16* fkh   = (u16*)alloc((size_t)1024 * 128 * 2);
    float* ps  = (float*)alloc((size_t)2 * 16 * 2048 * 4);
    float* ps2 = (float*)alloc((size_t)2 * 16 * 2048 * 4);
    float* scaleA = (float*)alloc((size_t)2 * 2048 * 4);
    float* shiftA = (float*)alloc((size_t)2 * 2048 * 4);
    int* counts = (int*)alloc(8192 * 4);
    int* colN   = (int*)alloc(1024 * 4);
    int* colP   = (int*)alloc(1024 * 4);

    // casts / transposes to bf16
    k_cast2<<<dim3(1024, 2), 256, 0, stream>>>(midq, midk, midqh, midkh,
                                               (long)1024 * 2048 / 4);
    dim3 tb(32, 8);
    k_castT<<<dim3(64, 64), tb, 0, stream>>>(W1, W1t, 2048, 2048);
    k_castT<<<dim3(256, 64), tb, 0, stream>>>(Wlin, WlinT, 2048, 8192);
    k_castT<<<dim3(4, 64), tb, 0, stream>>>(W2, W2t, 2048, 128);
    k_castT<<<dim3(1024, 4), tb, 0, stream>>>(nq, nqT, 128, 32768);

    // merged: H = X@W1+b1 (bf16, tiles 0..15) and logits = X@Wlin+blin
    // (f32, tiles 16..79), B = contiguous [W1t|WlinT]
    gemm_bt<4><<<dim3(8, 80, 2), 256, 0, stream>>>(midqh, midkh, W1t, nullptr,
        b1, blin, Hq, Hk, out + O2, out + O3, 2048, 2048, 0, 80, 2048, nullptr);

    k_bn_stats<<<dim3(8, 16, 2), 256, 0, stream>>>(Hq, Hk, ps, ps2);
    k_bn_final<<<16, 256, 0, stream>>>(ps, ps2, gamma, beta, scaleA, shiftA);
    k_bn_apply<<<dim3(1024, 2), 256, 0, stream>>>(Hq, Hk, scaleA, shiftA);

    hipMemsetAsync(counts, 0, 8192 * 4, stream);

    // F = G @ W2 (split-K=8, partial stores; reduced in k_l2norm)
    gemm_bt<2><<<dim3(8, 8, 2), 256, 0, stream>>>(Hq, Hk, W2t, nullptr, nullptr,
        nullptr, nullptr, nullptr, Fq, Fk, 2048, 2048, 128, 1, 256, nullptr);

    k_l2norm<<<dim3(1024, 2), 128, 0, stream>>>(Fq, Fk, b2, fqf, fkf, fqh, fkh,
                                                pq, lq, out + O0);

    // merged: sim_batch (tiles 0..7 -> cols [0,1024)) + neg_list
    // (tiles 8..263 -> remapped cols [1032,33796))
    gemm_bt<5><<<dim3(8, 264, 1), 256, 0, stream>>>(fqh, fqh, fkh, nqT,
        nullptr, nullptr, nullptr, nullptr, out + O0, out + O0,
        128, 128, 33796, 264, 128, lq);

    k_labels<<<dim3(17, 1024), 256, 0, stream>>>(lq, lk, out + O1);

    k_copy2<<<2048, 256, 0, stream>>>(nq, out + O4, 4194304 / 4,
                                      pq, out + O5, 8388608 / 4);

    k_rank<<<8, 128, 0, stream>>>(lk, nptr, pptr, counts, colN, colP);
    k_scatter_ptrs<<<544, 256, 0, stream>>>(fkf, colN, colP, nptr, pptr, counts,
                                            out + O4, out + O5, out + O6, out + O7);
}